// Round 8
// baseline (399.100 us; speedup 1.0000x reference)
//
#include <hip/hip_runtime.h>
#include <hip/hip_bf16.h>

#define NN 100000
#define NE 1200000
#define NE4 (NE / 4)                         // 300000
#define XCD_N 8
#define NPX (NN / XCD_N)                     // 12500 nodes per XCD
#define CAP 64                               // bucket capacity (P(deg>64) ~ 15 sigma)
#define SPILL_MAX 4096
#define AGG_GRID 50000                       // 6250 * 8: (half, nodegroup) from blockIdx

// ---------------- single-pass CSR-bucket build, XCD-partitioned ----------------
// block b (XCD = b&7, normal dispatch only -- R5: coop launch breaks this mapping)
// stripes the full edge list with its XCD's sibling blocks and handles only dsts
// in its 12500-node range: deg/bucket lines are written by exactly one XCD ->
// L2-local atomics, dirty lines evict once (R3: 85MB HBM writes without this).
__global__ __launch_bounds__(256) void bucket_fill_kernel(const int* __restrict__ esrc,
                                                          const int* __restrict__ edst,
                                                          int* __restrict__ deg,
                                                          int* __restrict__ bucket,
                                                          int* __restrict__ spill,
                                                          int* __restrict__ spill_cnt) {
    int xcd = blockIdx.x & 7;
    int sub = blockIdx.x >> 3;
    int nsub = gridDim.x >> 3;
    int lo = xcd * NPX;
    for (int i = sub * 256 + threadIdx.x; i < NE4; i += nsub * 256) {
        int4 d  = ((const int4*)edst)[i];
        int4 sr = ((const int4*)esrc)[i];
        #pragma unroll
        for (int c = 0; c < 4; ++c) {
            int dd = (c == 0) ? d.x : (c == 1) ? d.y : (c == 2) ? d.z : d.w;
            int ss = (c == 0) ? sr.x : (c == 1) ? sr.y : (c == 2) ? sr.z : sr.w;
            if ((unsigned)(dd - lo) < NPX) {
                int slot = atomicAdd(&deg[dd], 1);
                if (slot < CAP) {
                    bucket[dd * CAP + slot] = ss;
                } else {
                    int p = atomicAdd(spill_cnt, 1);
                    if (p < SPILL_MAX) { spill[2 * p] = dd; spill[2 * p + 1] = ss; }
                }
            }
        }
    }
}

// ---------------- per-node matmul ----------------
// MODE 0: v = x[n][f] (f32);  MODE 1: v = relu(din*ah[n][f]+bias[f]) (ah bf16)
// writes bf16( din * (v_row @ W) ) SPLIT into ul (f<32) / uh (f>=32): 64B rows
// so each gather in agg is exactly one cache line of its half.
template <int MODE>
__global__ __launch_bounds__(256) void mm_kernel(const void* __restrict__ in,
                                                 const float* __restrict__ W,
                                                 const float* __restrict__ bias,
                                                 const int* __restrict__ deg,
                                                 __hip_bfloat16* __restrict__ ul,
                                                 __hip_bfloat16* __restrict__ uh) {
    __shared__ float Ws[64 * 64];
    __shared__ float hrow[4][64];
    int tid = threadIdx.x;
    {   // stage W (16 KB) via float4
        const float4* Wv = (const float4*)W;
        float4* Wsv = (float4*)Ws;
        #pragma unroll
        for (int i = 0; i < 4; ++i) Wsv[tid + 256 * i] = Wv[tid + 256 * i];
    }
    int local = tid >> 6;            // node within block
    int f = tid & 63;                // feature
    int n = blockIdx.x * 4 + local;  // NN divisible by 4
    float din = rsqrtf((float)(deg[n] + 1));
    float v;
    if (MODE == 0) {
        v = ((const float*)in)[n * 64 + f];
    } else {
        v = __bfloat162float(((const __hip_bfloat16*)in)[n * 64 + f]);
        v = fmaxf(fmaf(din, v, bias[f]), 0.f);
    }
    hrow[local][f] = v;
    __syncthreads();
    float acc = 0.f;
    #pragma unroll
    for (int k = 0; k < 64; ++k)
        acc = fmaf(hrow[local][k], Ws[k * 64 + f], acc);
    __hip_bfloat16 r = __float2bfloat16(din * acc);
    if (f < 32) ul[n * 32 + f] = r;
    else        uh[n * 32 + (f - 32)] = r;
}

// ---------------- half-row aggregation core ----------------
// wave = 8 edge-groups x 8 lanes; lane covers features [fo*4, fo*4+4) of its
// HALF via one dwordx2 (8B): one load instruction = 8 x 64B-line gathers in
// flight, each gather exactly one cache line. Bucket row batch-loaded once
// (coalesced) and broadcast by shfl. On exit acc[0..4) = aggregated half-row
// (self + neighbors), replicated across the 8 groups.
__device__ __forceinline__ void acc_bf4(float acc[4], uint2 v) {
    acc[0] += __uint_as_float(v.x << 16);
    acc[1] += __uint_as_float(v.x & 0xffff0000u);
    acc[2] += __uint_as_float(v.y << 16);
    acc[3] += __uint_as_float(v.y & 0xffff0000u);
}

__device__ __forceinline__ unsigned packbf2(float lof, float hif) {
    __hip_bfloat16 l = __float2bfloat16(lof), h = __float2bfloat16(hif);
    unsigned short ull, uhh;
    __builtin_memcpy(&ull, &l, 2);
    __builtin_memcpy(&uhh, &h, 2);
    return ((unsigned)uhh << 16) | ull;
}

__device__ __forceinline__ void agg_row_half(const int* __restrict__ degv,
                                             const int* __restrict__ bucket,
                                             const uint2* __restrict__ u2,
                                             const int* __restrict__ spill,
                                             const int* __restrict__ spill_cnt,
                                             int n, int lane, int grp, int fo,
                                             float acc[4]) {
    float acc2[4];
    #pragma unroll
    for (int i = 0; i < 4; ++i) { acc[i] = 0.f; acc2[i] = 0.f; }
    int deg = degv[n];
    int dc = deg < CAP ? deg : CAP;
    int cidx = -1;
    if (lane < dc) cidx = bucket[n * CAP + lane];    // one coalesced row load
    if (grp == 0) acc_bf4(acc, u2[n * 8 + fo]);      // self loop
    int s0 = __shfl(cidx, grp);                      // sweep 0: edges 0..7
    int s1 = __shfl(cidx, grp + 8);                  // sweep 1: edges 8..15
    if (grp < dc) acc_bf4(acc, u2[s0 * 8 + fo]);
    if (grp + 8 < dc) acc_bf4(acc2, u2[s1 * 8 + fo]);
    for (int j = grp + 16; j < dc; j += 8) {         // deg in (16,64]
        int s = __shfl(cidx, j);
        acc_bf4(acc, u2[s * 8 + fo]);
    }
    if (deg > CAP) {                                 // spill drain: ~never taken
        int cnt = *spill_cnt; if (cnt > SPILL_MAX) cnt = SPILL_MAX;
        for (int e = 0; e < cnt; ++e) {
            if (spill[2 * e] == n && grp == 0)
                acc_bf4(acc2, u2[spill[2 * e + 1] * 8 + fo]);
        }
    }
    #pragma unroll
    for (int i = 0; i < 4; ++i) {                    // merge sweeps + 8 groups
        float v = acc[i] + acc2[i];
        v += __shfl_xor(v, 8);
        v += __shfl_xor(v, 16);
        v += __shfl_xor(v, 32);
        acc[i] = v;
    }
}

// ---------------- aggregate, XCD-bound halves ----------------
// 50000 blocks: blockIdx = m*8 + k, XCD = k (round-robin, R4-proven for normal
// dispatch), half = k>>2 (XCDs 0-3 gather ul only, 4-7 uh only -> per-XCD gather
// working set 6.4MB vs 12.8, request/line/XCD 1.5 -> 3: the L2-residency bet),
// nodegroup g = m*4 + (k&3) in [0,25000): bijective coverage of all nodes for
// each half regardless of the true blockIdx->XCD mapping.
// One wave per (node, half), no serial nodes (R1/R2 lesson).
// POOL=0: write bf16 half-row to ah[n][64]. POOL=1: global pool into gp.
template <int POOL>
__global__ __launch_bounds__(256, 8) void agg_kernel(const int* __restrict__ degv,
                                                     const int* __restrict__ bucket,
                                                     const uint2* __restrict__ ulv,
                                                     const uint2* __restrict__ uhv,
                                                     const int* __restrict__ spill,
                                                     const int* __restrict__ spill_cnt,
                                                     __hip_bfloat16* __restrict__ ah,
                                                     float* __restrict__ gp) {
    __shared__ float gpart[32];
    int tid = threadIdx.x;
    if (POOL) {
        if (tid < 32) gpart[tid] = 0.f;
        __syncthreads();
    }
    int k = blockIdx.x & 7;
    int half = k >> 2;
    int g = (blockIdx.x >> 3) * 4 + (k & 3);
    const uint2* u2 = half ? uhv : ulv;
    int lane = tid & 63;
    int grp = lane >> 3;
    int fo = lane & 7;
    int n = g * 4 + (tid >> 6);
    float acc[4];
    agg_row_half(degv, bucket, u2, spill, spill_cnt, n, lane, grp, fo, acc);
    if (POOL) {
        if (grp == 0) {                               // lanes 0..7 hold the half row
            float din = rsqrtf((float)(degv[n] + 1));
            #pragma unroll
            for (int i = 0; i < 4; ++i) atomicAdd(&gpart[fo * 4 + i], din * acc[i]);
        }
        __syncthreads();
        if (tid < 32) atomicAdd(&gp[(blockIdx.x & 63) * 64 + half * 32 + tid], gpart[tid]);
    } else {
        if (grp == 0) {                               // 8 lanes x 8B bf16 = the 64B half-row
            uint2 pv;
            pv.x = packbf2(acc[0], acc[1]);
            pv.y = packbf2(acc[2], acc[3]);
            ((uint2*)ah)[n * 16 + half * 8 + fo] = pv;
        }
    }
}

// ---------------- head: g = colsum(gp) + N*b2;  out = g @ Wl + bl ----------------
__global__ __launch_bounds__(64) void head_kernel(const float* __restrict__ gp,
                                                  const float* __restrict__ b2,
                                                  const float* __restrict__ Wl,
                                                  const float* __restrict__ bl,
                                                  float* __restrict__ out) {
    int t = threadIdx.x;  // one wave
    float s = 0.f;
    #pragma unroll 8
    for (int r = 0; r < 64; ++r) s += gp[r * 64 + t];
    float gf = s + (float)NN * b2[t];
    #pragma unroll
    for (int c = 0; c < 10; ++c) {
        float p = gf * Wl[t * 10 + c];
        #pragma unroll
        for (int off = 32; off > 0; off >>= 1) p += __shfl_down(p, off);
        if (t == 0) out[c] = p + bl[c];
    }
}

extern "C" void kernel_launch(void* const* d_in, const int* in_sizes, int n_in,
                              void* d_out, int out_size, void* d_ws, size_t ws_size,
                              hipStream_t stream) {
    const float* x  = (const float*)d_in[0];
    const int* eidx = (const int*)d_in[1];
    const int* esrc = eidx;        // edge_idx[0]
    const int* edst = eidx + NE;   // edge_idx[1]
    const float* W0 = (const float*)d_in[2];
    const float* b0 = (const float*)d_in[3];
    const float* W1 = (const float*)d_in[4];
    const float* b1 = (const float*)d_in[5];
    const float* W2 = (const float*)d_in[6];
    const float* b2 = (const float*)d_in[7];
    const float* Wl = (const float*)d_in[8];
    const float* bl = (const float*)d_in[9];
    float* out = (float*)d_out;

    // workspace layout (4-byte units); all arrays 16B-aligned
    float* ws = (float*)d_ws;
    size_t off = 0;
    int*   deg    = (int*)(ws + off); off += NN;
    __hip_bfloat16* ah = (__hip_bfloat16*)(ws + off); off += (size_t)NN * 32;  // bf16 N*64
    __hip_bfloat16* ul = (__hip_bfloat16*)(ws + off); off += (size_t)NN * 16;  // bf16 N*32
    __hip_bfloat16* uh = (__hip_bfloat16*)(ws + off); off += (size_t)NN * 16;  // bf16 N*32
    float* gp     =        ws + off;  off += 64 * 64;                          // pool partials
    int*   spill_cnt = (int*)(ws + off); off += 4;                             // adjacent to gp: one memset
    int*   spill  = (int*)(ws + off); off += 2 * SPILL_MAX;
    int*   bucket = (int*)(ws + off); off += (size_t)NN * CAP;                 // 25.6 MB

    hipMemsetAsync(deg, 0, NN * sizeof(int), stream);
    hipMemsetAsync(gp, 0, (64 * 64 + 4) * sizeof(float), stream);  // gp + spill_cnt

    // single-pass bucket CSR build (normal dispatch: R5 proved coop launch breaks b&7->XCD)
    bucket_fill_kernel<<<2048, 256, 0, stream>>>(esrc, edst, deg, bucket, spill, spill_cnt);

    // layer 0 matmul: ul/uh = bf16(din*(x@W0))
    mm_kernel<0><<<NN / 4, 256, 0, stream>>>(x, W0, nullptr, deg, ul, uh);
    // layer 0 agg -> ah
    agg_kernel<0><<<AGG_GRID, 256, 0, stream>>>(deg, bucket, (const uint2*)ul, (const uint2*)uh,
                                                spill, spill_cnt, ah, gp);
    // layer 1 matmul: finalize(b0) + W1 -> ul/uh
    mm_kernel<1><<<NN / 4, 256, 0, stream>>>(ah, W1, b0, deg, ul, uh);
    // layer 1 agg -> ah
    agg_kernel<0><<<AGG_GRID, 256, 0, stream>>>(deg, bucket, (const uint2*)ul, (const uint2*)uh,
                                                spill, spill_cnt, ah, gp);
    // layer 2 matmul: finalize(b1) + W2 -> ul/uh
    mm_kernel<1><<<NN / 4, 256, 0, stream>>>(ah, W2, b1, deg, ul, uh);
    // layer 2 agg + global pool (din folded; N*b2 added in head)
    agg_kernel<1><<<AGG_GRID, 256, 0, stream>>>(deg, bucket, (const uint2*)ul, (const uint2*)uh,
                                                spill, spill_cnt, ah, gp);
    head_kernel<<<1, 64, 0, stream>>>(gp, b2, Wl, bl, out);
}